// Round 8
// baseline (221.658 us; speedup 1.0000x reference)
//
#include <hip/hip_runtime.h>

// ExactAttention: block-diagonal masked softmax(Q K^T / sqrt(d)) @ V
// N=12288, D=128, 32 sorted batch segments, fp32 in/out.
// Global-max/EPS deviation ~1e-8 relative -> plain masked softmax.
//
// R8 = R7 (DMA double-buffered attn, splitK=4, channel-spread Vtb) with the
// combine kernel FOLDED into attn via last-arriver reduction: each split WG
// writes fp32 partials, fences, bumps a per-row-group device-scope counter;
// the 4th arriver re-reads all 4 partials and writes normalized out. Saves
// one launch + combine dispatch. cnt[] zeroed by prep (ws re-poisoned 0xAA).

#define NN 12288
#define DD 128
#define NB 32
#define PS_LD 40
#define VTS 12424   // Vtb row stride (shorts): spreads L2 channels c -> c%16

typedef __attribute__((ext_vector_type(8))) short short8;
typedef __attribute__((ext_vector_type(4))) float float4v;

__device__ __forceinline__ short f2bf(float f) {
  unsigned u = __builtin_bit_cast(unsigned, f);
  return (short)((u + 0x7FFFu + ((u >> 16) & 1u)) >> 16);
}

__device__ __forceinline__ short8 ld8_bf16(const float* p) {
  float4v f0 = *(const float4v*)p;
  float4v f1 = *(const float4v*)(p + 4);
  short8 s;
  s[0] = f2bf(f0[0]); s[1] = f2bf(f0[1]); s[2] = f2bf(f0[2]); s[3] = f2bf(f0[3]);
  s[4] = f2bf(f1[0]); s[5] = f2bf(f1[1]); s[6] = f2bf(f1[2]); s[7] = f2bf(f1[3]);
  return s;
}

// async global->LDS DMA, 16B/lane: lds dest = uniform base + lane*16.
__device__ __forceinline__ void dma16(const short* gsrc, short* ldst) {
  auto g = (const __attribute__((address_space(1))) void*)(unsigned long long)gsrc;
  auto l = (__attribute__((address_space(3))) void*)(unsigned)(unsigned long long)ldst;
  __builtin_amdgcn_global_load_lds(g, l, 16, 0, 0);
}

// ---------- prep: Kb = bf16(K); Vtb = bf16(V)^T; starts[]; cnt[]=0 ----------
__global__ __launch_bounds__(256) void prep_kernel(
    const float* __restrict__ K, const float* __restrict__ V,
    const int* __restrict__ seg,
    short* __restrict__ Kb, short* __restrict__ Vtb, int* __restrict__ starts,
    unsigned* __restrict__ cnt) {
  const int tid = threadIdx.x;
  const int b = blockIdx.x;
  if (b < 768) {
    const size_t base = (size_t)b * 2048 + (size_t)tid * 8;
    *(short8*)(Kb + base) = ld8_bf16(K + base);
  } else if (b < 864) {
    __shared__ __align__(16) short Ts[DD * 136];
    const int kt = (b - 768) * 128;
#pragma unroll
    for (int rep = 0; rep < 16; ++rep) {
      int v = rep * 256 + tid;            // [128 keys][32 float4-cols]
      int key = v >> 5, c4 = (v & 31) * 4;
      float4v f = *(const float4v*)(V + (size_t)(kt + key) * DD + c4);
      Ts[(c4 + 0) * 136 + key] = f2bf(f[0]);
      Ts[(c4 + 1) * 136 + key] = f2bf(f[1]);
      Ts[(c4 + 2) * 136 + key] = f2bf(f[2]);
      Ts[(c4 + 3) * 136 + key] = f2bf(f[3]);
    }
    __syncthreads();
    const int c16 = (tid & 15) * 8;
#pragma unroll
    for (int rep = 0; rep < 8; ++rep) {
      int d = rep * 16 + (tid >> 4);
      short8 s = *(const short8*)&Ts[d * 136 + c16];
      *(short8*)(Vtb + (size_t)d * VTS + kt + c16) = s;
    }
  } else if (b < 912) {
    int i = (b - 864) * 256 + tid;
    int s = seg[i];
    int sp = (i == 0) ? -1 : seg[i - 1];
    for (int bb = sp + 1; bb <= s; ++bb) starts[bb] = i;
    if (i == NN - 1)
      for (int bb = s + 1; bb <= NB; ++bb) starts[bb] = NN;
  } else {
    if (tid < 192) cnt[tid] = 0u;   // per-row-group split counters
  }
}

// issue one 32-key tile's DMAs (this wave's quarter: 2 K-instr + 2 V-instr)
__device__ __forceinline__ void issue_tile(
    const short* __restrict__ Kb, const short* __restrict__ Vtb,
    short* KshP, short* VshP, int j0, int wave, int lane) {
  // K tile: 32 rows x 256B, chunk m of row r stored at pos m^(r&15)
#pragma unroll
  for (int i = 0; i < 2; ++i) {
    const int R = wave * 8 + i * 4;           // 4 rows per instr
    const int row = R + (lane >> 4);
    const int dchunk = (lane & 15) ^ (row & 15);
    dma16(Kb + (size_t)(j0 + row) * DD + dchunk * 8, KshP + R * 128);
  }
  // V tile: 128 d-rows x 64B, chunk m of row d stored at pos m^(d&3)
#pragma unroll
  for (int i = 0; i < 2; ++i) {
    const int D = wave * 32 + i * 16;         // 16 rows per instr
    const int dr = D + (lane >> 2);
    const int vchunk = (lane & 3) ^ ((lane >> 2) & 3);   // dr&3 == (lane>>2)&3
    dma16(Vtb + (size_t)dr * VTS + j0 + vchunk * 8, VshP + D * 32);
  }
}

// ---------- attention + fused last-arriver combine ----------
__global__ __launch_bounds__(256, 3) void attn_kernel(
    const float* __restrict__ Q, const short* __restrict__ Kb,
    const short* __restrict__ Vtb, const int* __restrict__ seg,
    const int* __restrict__ starts,
    float* __restrict__ Op, float* __restrict__ lp,
    unsigned* __restrict__ cnt, float* __restrict__ out) {
  __shared__ __align__(16) short Ksh[2][32 * 128];   // 16 KB (swizzled)
  __shared__ __align__(16) short Vsh[2][128 * 32];   // 16 KB (swizzled)
  __shared__ __align__(16) short Ps[4][16 * PS_LD];  // 5 KB per-wave P
  __shared__ int sflag;

  const int tid = threadIdx.x;
  const int wave = tid >> 6;
  const int lane = tid & 63;
  const int c = lane & 15;
  const int quad = lane >> 4;

  // bid = xcd + 8*y; XCD x gets 24 contiguous row-groups (L2 segment reuse)
  const int bid = blockIdx.x;
  const int y = bid >> 3;
  const int rg = (bid & 7) * 24 + (y >> 2);
  const int sk = y & 3;                       // split-K index
  const int i0 = rg * 64;
  const int i0w = i0 + wave * 16;

  // key range of this WG's 64 rows, then this split's 32-chunk slice
  const int L = starts[seg[i0]];
  const int H = starts[seg[i0 + 63] + 1];
  const int Lm = L & ~31;
  const int nck = (H - Lm + 31) >> 5;
  const int ck0 = (nck * sk) >> 2;
  const int ck1 = (nck * (sk + 1)) >> 2;
  const int nt = ck1 - ck0;                   // tiles for this split (uniform)

  // per-row key ranges for masking
  int st_r[4], en_r[4];
#pragma unroll
  for (int r = 0; r < 4; ++r) {
    int s = seg[i0w + quad * 4 + r];
    st_r[r] = starts[s];
    en_r[r] = starts[s + 1];
  }

  // resident Q A-frags for this wave's 16 rows
  short8 qf[4];
  {
    const float* qrow = Q + (size_t)(i0w + c) * DD + quad * 8;
#pragma unroll
    for (int kc = 0; kc < 4; ++kc) qf[kc] = ld8_bf16(qrow + kc * 32);
  }

  float4v acc[8];
#pragma unroll
  for (int n = 0; n < 8; ++n) acc[n] = (float4v){0.f, 0.f, 0.f, 0.f};
  float l_part[4] = {0.f, 0.f, 0.f, 0.f};

  const float scale = 0.08838834764831845f;   // 1/sqrt(128)

  if (nt > 0)
    issue_tile(Kb, Vtb, &Ksh[0][0], &Vsh[0][0], Lm + ck0 * 32, wave, lane);
  __syncthreads();   // drains tile-0 DMA (vmcnt(0) before s_barrier)

  for (int t = 0; t < nt; ++t) {
    const int j0 = Lm + (ck0 + t) * 32;
    const int p = t & 1;
    if (t + 1 < nt)
      issue_tile(Kb, Vtb, &Ksh[p ^ 1][0], &Vsh[p ^ 1][0], j0 + 32, wave, lane);

    // --- S = Q K^T (16 rows x 32 keys), K from swizzled LDS ---
    float4v s0 = (float4v){0.f, 0.f, 0.f, 0.f};
    float4v s1 = (float4v){0.f, 0.f, 0.f, 0.f};
    const short* Kp = &Ksh[p][0];
#pragma unroll
    for (int kc = 0; kc < 4; ++kc) {
      const int pos = ((kc * 4 + quad) ^ c) * 8;
      short8 b0 = *(const short8*)(Kp + c * 128 + pos);          // keys j0+c
      short8 b1 = *(const short8*)(Kp + (16 + c) * 128 + pos);   // keys j0+16+c
      s0 = __builtin_amdgcn_mfma_f32_16x16x32_bf16(qf[kc], b0, s0, 0, 0, 0);
      s1 = __builtin_amdgcn_mfma_f32_16x16x32_bf16(qf[kc], b1, s1, 0, 0, 0);
    }

    // --- mask (range compare), exp, l partials, P -> LDS (C->A layout) ---
    const int ja = j0 + c, jb = ja + 16;
    short* prow = &Ps[wave][0];
#pragma unroll
    for (int r = 0; r < 4; ++r) {
      float pa = (ja >= st_r[r] && ja < en_r[r]) ? __expf(s0[r] * scale) : 0.f;
      float pb = (jb >= st_r[r] && jb < en_r[r]) ? __expf(s1[r] * scale) : 0.f;
      l_part[r] += pa + pb;
      int row = quad * 4 + r;
      prow[row * PS_LD + c]      = f2bf(pa);
      prow[row * PS_LD + 16 + c] = f2bf(pb);
    }
    short8 pf = *(const short8*)&Ps[wave][c * PS_LD + quad * 8];

    // --- O += P V, V^T from swizzled LDS ---
    const short* Vp = &Vsh[p][0];
    const int vpos = (quad ^ (c & 3)) * 8;
#pragma unroll
    for (int n = 0; n < 8; ++n) {
      short8 vf = *(const short8*)(Vp + (n * 16 + c) * 32 + vpos);
      acc[n] = __builtin_amdgcn_mfma_f32_16x16x32_bf16(pf, vf, acc[n], 0, 0, 0);
    }

    __syncthreads();  // drains next-tile DMA + all LDS reads before overwrite
  }

  // in-wave l reduction over the 16 key-columns
  float lrow[4];
#pragma unroll
  for (int r = 0; r < 4; ++r) {
    float l = l_part[r];
    l += __shfl_xor(l, 1, 64);
    l += __shfl_xor(l, 2, 64);
    l += __shfl_xor(l, 4, 64);
    l += __shfl_xor(l, 8, 64);
    lrow[r] = l;
  }

  // write fp32 partials (always, even nt==0)
  float* OpW = Op + ((size_t)sk * NN + i0w) * DD;
#pragma unroll
  for (int n = 0; n < 8; ++n)
#pragma unroll
    for (int r = 0; r < 4; ++r)
      OpW[(quad * 4 + r) * DD + n * 16 + c] = acc[n][r];
  if (c == 0) {
#pragma unroll
    for (int r = 0; r < 4; ++r) lp[sk * NN + i0w + quad * 4 + r] = lrow[r];
  }

  // --- last-arriver combine (fence + device-scope counter) ---
  __threadfence();      // make this thread's partials visible device-wide
  __syncthreads();      // all threads' fences complete before the atomic
  if (tid == 0) sflag = (atomicAdd(&cnt[rg], 1u) == 3u);
  __syncthreads();
  if (sflag) {
    __threadfence();    // acquire: don't read stale partials
#pragma unroll
    for (int rep = 0; rep < 8; ++rep) {
      int u = rep * 256 + tid;               // [64 rows][32 f4-cols]
      int row = u >> 5, c4 = (u & 31) * 4;
      int grow = i0 + row;
      float l = lp[grow] + lp[NN + grow] + lp[2 * NN + grow] + lp[3 * NN + grow];
      float4v o = (float4v){0.f, 0.f, 0.f, 0.f};
#pragma unroll
      for (int s = 0; s < 4; ++s) {
        float4v t = *(const float4v*)(Op + ((size_t)s * NN + grow) * DD + c4);
        o[0] += t[0]; o[1] += t[1]; o[2] += t[2]; o[3] += t[3];
      }
      float inv = 1.f / (l + 1e-8f);
      o[0] *= inv; o[1] *= inv; o[2] *= inv; o[3] *= inv;
      *(float4v*)(out + (size_t)grow * DD + c4) = o;
    }
  }
}

// ---------- fallback (verified R1 kernel) if ws_size is too small ----------
#define KT_LD 136
#define VT_LD 40
typedef __attribute__((ext_vector_type(4))) short short4v;

__global__ __launch_bounds__(256) void attn_fallback(
    const float* __restrict__ Q, const float* __restrict__ K,
    const float* __restrict__ V, const int* __restrict__ seg,
    float* __restrict__ out) {
  __shared__ __align__(16) short Kt[32 * KT_LD];
  __shared__ __align__(16) short Vt[DD * VT_LD];
  __shared__ __align__(16) short Ps[4][16 * PS_LD];
  const int tid = threadIdx.x, wave = tid >> 6, lane = tid & 63;
  const int c = lane & 15, quad = lane >> 4;
  const int m0 = blockIdx.x * 64, i0 = m0 + wave * 16;
  const int segFirst = seg[m0], segLast = seg[m0 + 63];
  int lo = 0, hb = NN;
  while (lo < hb) { int mid = (lo + hb) >> 1; if (seg[mid] < segFirst) lo = mid + 1; else hb = mid; }
  int hi = lo, hb2 = NN;
  while (hi < hb2) { int mid = (hi + hb2) >> 1; if (seg[mid] <= segLast) hi = mid + 1; else hb2 = mid; }
  short8 qf[4];
  const float* qrow = Q + (size_t)(i0 + c) * DD + quad * 8;
#pragma unroll
  for (int kc = 0; kc < 4; ++kc) qf[kc] = ld8_bf16(qrow + kc * 32);
  int seg_r[4];
#pragma unroll
  for (int r = 0; r < 4; ++r) seg_r[r] = seg[i0 + quad * 4 + r];
  float4v acc[8];
#pragma unroll
  for (int n = 0; n < 8; ++n) acc[n] = (float4v){0.f, 0.f, 0.f, 0.f};
  float l_part[4] = {0.f, 0.f, 0.f, 0.f};
  const float scale = 0.08838834764831845f;
  for (int j0 = lo; j0 < hi; j0 += 32) {
    __syncthreads();
    {
      int row = tid >> 3, ch = tid & 7;
      int jj = j0 + row; if (jj > NN - 1) jj = NN - 1;
      const float* kp = K + (size_t)jj * DD + ch * 16;
      short* dst = &Kt[row * KT_LD + ch * 16];
#pragma unroll
      for (int q4 = 0; q4 < 4; ++q4) {
        float4v f = *(const float4v*)(kp + q4 * 4);
        short4v s;
        s[0] = f2bf(f[0]); s[1] = f2bf(f[1]); s[2] = f2bf(f[2]); s[3] = f2bf(f[3]);
        *(short4v*)(dst + q4 * 4) = s;
      }
    }
    {
      int d = tid & 127, jh = tid >> 7;
      float vv[16];
#pragma unroll
      for (int j = 0; j < 16; ++j) {
        int jj = j0 + jh * 16 + j; if (jj > NN - 1) jj = NN - 1;
        vv[j] = V[(size_t)jj * DD + d];
      }
      short8 a, b2;
#pragma unroll
      for (int j = 0; j < 8; ++j) { a[j] = f2bf(vv[j]); b2[j] = f2bf(vv[8 + j]); }
      *(short8*)&Vt[d * VT_LD + jh * 16] = a;
      *(short8*)&Vt[d * VT_LD + jh * 16 + 8] = b2;
    }
    __syncthreads();
    float4v s0 = (float4v){0.f, 0.f, 0.f, 0.f};
    float4v s1 = (float4v){0.f, 0.f, 0.f, 0.f};
    const short* krow0 = &Kt[c * KT_LD + quad * 8];
    const short* krow1 = &Kt[(16 + c) * KT_LD + quad * 8];
#pragma unroll
    for (int kc = 0; kc < 4; ++kc) {
      short8 b0 = *(const short8*)(krow0 + kc * 32);
      short8 b1 = *(const short8*)(krow1 + kc * 32);
      s0 = __builtin_amdgcn_mfma_f32_16x16x32_bf16(qf[kc], b0, s0, 0, 0, 0);
      s1 = __builtin_amdgcn_mfma_f32_16x16x32_bf16(qf[kc], b1, s1, 0, 0, 0);
    }
    int ja = j0 + c, jb = ja + 16;
    int sa = seg[ja < NN ? ja : NN - 1];
    int sb = seg[jb < NN ? jb : NN - 1];
    bool va = ja < hi, vb = jb < hi;
    short* prow = &Ps[wave][0];
#pragma unroll
    for (int r = 0; r < 4; ++r) {
      float pa = (va && sa == seg_r[r]) ? __expf(s0[r] * scale) : 0.f;
      float pb = (vb && sb == seg_r[r]) ? __expf(s1[r] * scale) : 0.f;
      l_part[r] += pa + pb;
      int row = quad * 4 + r;
      prow[row * PS_LD + c] = f2bf(pa);
      prow[row * PS_LD + 16 + c] = f2bf(pb);
    }
    short8 pf = *(const short8*)&Ps[wave][c * PS_LD + quad * 8];
#pragma unroll
    for (int n = 0; n < 8; ++n) {
      short8 vfr = *(const short8*)&Vt[(n * 16 + c) * VT_LD + quad * 8];
      acc[n] = __builtin_amdgcn_mfma_f32_16x16x32_bf16(pf, vfr, acc[n], 0, 0, 0);
    }
  }
  float linv[4];
#pragma unroll
  for (int r = 0; r < 4; ++r) {
    float l = l_part[r];
    l += __shfl_xor(l, 1, 64);
    l += __shfl_xor(l, 2, 64);
    l += __shfl_xor(l, 4, 64);
    l += __shfl_xor(l, 8, 64);
    linv[r] = 1.f / (l + 1e-8f);
  }
#pragma unroll
  for (int n = 0; n < 8; ++n)
#pragma unroll
    for (int r = 0; r < 4; ++r)
      out[(size_t)(i0 + quad * 4 + r) * DD + n * 16 + c] = acc[n][r] * linv[r];
}

extern "C" void kernel_launch(void* const* d_in, const int* in_sizes, int n_in,
                              void* d_out, int out_size, void* d_ws, size_t ws_size,
                              hipStream_t stream) {
  const float* Q = (const float*)d_in[0];
  const float* K = (const float*)d_in[1];
  const float* V = (const float*)d_in[2];
  const int* seg = (const int*)d_in[4];
  float* out = (float*)d_out;

  const size_t kb_bytes = (size_t)NN * DD * sizeof(short);      // 3,145,728
  const size_t vt_bytes = (size_t)DD * VTS * sizeof(short);     // 3,180,544
  const size_t st_bytes = 64 * sizeof(int);                     // 256
  const size_t op_bytes = (size_t)4 * NN * DD * sizeof(float);  // 25,165,824
  const size_t lp_bytes = (size_t)4 * NN * sizeof(float);       // 196,608
  const size_t ct_bytes = 192 * sizeof(unsigned);               // 768
  const size_t need = kb_bytes + vt_bytes + st_bytes + op_bytes + lp_bytes + ct_bytes;

  if (ws_size >= need) {
    char* w = (char*)d_ws;
    short* Kb  = (short*)w;                     w += kb_bytes;
    short* Vtb = (short*)w;                     w += vt_bytes;
    int* starts = (int*)w;                      w += st_bytes;
    float* Op = (float*)w;                      w += op_bytes;
    float* lp = (float*)w;                      w += lp_bytes;
    unsigned* cnt = (unsigned*)w;
    prep_kernel<<<913, 256, 0, stream>>>(K, V, seg, Kb, Vtb, starts, cnt);
    attn_kernel<<<768, 256, 0, stream>>>(Q, Kb, Vtb, seg, starts, Op, lp, cnt, out);
  } else {
    attn_fallback<<<NN / 64, 256, 0, stream>>>(Q, K, V, seg, out);
  }
}

// Round 9
// 95.520 us; speedup vs baseline: 2.3205x; 2.3205x over previous
//
#include <hip/hip_runtime.h>

// ExactAttention: block-diagonal masked softmax(Q K^T / sqrt(d)) @ V
// N=12288, D=128, 32 sorted batch segments, fp32 in/out.
// Global-max/EPS deviation ~1e-8 relative -> plain masked softmax.
//
// R9 = revert to R7 (prep -> DMA-pipelined attn -> combine; NO device-scope
// fences: R8 showed __threadfence() per-WG costs ~+125us via cross-XCD L2
// writeback) + one delta: attn __launch_bounds__(256,4) -> 4 WG/CU
// co-residency (LDS 37.5KB x 4 = 150 <= 160 KiB), more latency overlap.

#define NN 12288
#define DD 128
#define NB 32
#define PS_LD 40
#define VTS 12424   // Vtb row stride (shorts): spreads L2 channels c -> c%16

typedef __attribute__((ext_vector_type(8))) short short8;
typedef __attribute__((ext_vector_type(4))) float float4v;

__device__ __forceinline__ short f2bf(float f) {
  unsigned u = __builtin_bit_cast(unsigned, f);
  return (short)((u + 0x7FFFu + ((u >> 16) & 1u)) >> 16);
}

__device__ __forceinline__ short8 ld8_bf16(const float* p) {
  float4v f0 = *(const float4v*)p;
  float4v f1 = *(const float4v*)(p + 4);
  short8 s;
  s[0] = f2bf(f0[0]); s[1] = f2bf(f0[1]); s[2] = f2bf(f0[2]); s[3] = f2bf(f0[3]);
  s[4] = f2bf(f1[0]); s[5] = f2bf(f1[1]); s[6] = f2bf(f1[2]); s[7] = f2bf(f1[3]);
  return s;
}

// async global->LDS DMA, 16B/lane: lds dest = uniform base + lane*16.
__device__ __forceinline__ void dma16(const short* gsrc, short* ldst) {
  auto g = (const __attribute__((address_space(1))) void*)(unsigned long long)gsrc;
  auto l = (__attribute__((address_space(3))) void*)(unsigned)(unsigned long long)ldst;
  __builtin_amdgcn_global_load_lds(g, l, 16, 0, 0);
}

// ---------- prep: Kb = bf16(K); Vtb = bf16(V)^T (stride VTS); starts[] -----
__global__ __launch_bounds__(256) void prep_kernel(
    const float* __restrict__ K, const float* __restrict__ V,
    const int* __restrict__ seg,
    short* __restrict__ Kb, short* __restrict__ Vtb, int* __restrict__ starts) {
  const int tid = threadIdx.x;
  const int b = blockIdx.x;
  if (b < 768) {
    const size_t base = (size_t)b * 2048 + (size_t)tid * 8;
    *(short8*)(Kb + base) = ld8_bf16(K + base);
  } else if (b < 864) {
    __shared__ __align__(16) short Ts[DD * 136];
    const int kt = (b - 768) * 128;
#pragma unroll
    for (int rep = 0; rep < 16; ++rep) {
      int v = rep * 256 + tid;            // [128 keys][32 float4-cols]
      int key = v >> 5, c4 = (v & 31) * 4;
      float4v f = *(const float4v*)(V + (size_t)(kt + key) * DD + c4);
      Ts[(c4 + 0) * 136 + key] = f2bf(f[0]);
      Ts[(c4 + 1) * 136 + key] = f2bf(f[1]);
      Ts[(c4 + 2) * 136 + key] = f2bf(f[2]);
      Ts[(c4 + 3) * 136 + key] = f2bf(f[3]);
    }
    __syncthreads();
    const int c16 = (tid & 15) * 8;
#pragma unroll
    for (int rep = 0; rep < 8; ++rep) {
      int d = rep * 16 + (tid >> 4);
      short8 s = *(const short8*)&Ts[d * 136 + c16];
      *(short8*)(Vtb + (size_t)d * VTS + kt + c16) = s;
    }
  } else {
    int i = (b - 864) * 256 + tid;
    int s = seg[i];
    int sp = (i == 0) ? -1 : seg[i - 1];
    for (int bb = sp + 1; bb <= s; ++bb) starts[bb] = i;
    if (i == NN - 1)
      for (int bb = s + 1; bb <= NB; ++bb) starts[bb] = NN;
  }
}

// issue one 32-key tile's DMAs (this wave's quarter: 2 K-instr + 2 V-instr)
__device__ __forceinline__ void issue_tile(
    const short* __restrict__ Kb, const short* __restrict__ Vtb,
    short* KshP, short* VshP, int j0, int wave, int lane) {
  // K tile: 32 rows x 256B, chunk m of row r stored at pos m^(r&15)
#pragma unroll
  for (int i = 0; i < 2; ++i) {
    const int R = wave * 8 + i * 4;           // 4 rows per instr
    const int row = R + (lane >> 4);
    const int dchunk = (lane & 15) ^ (row & 15);
    dma16(Kb + (size_t)(j0 + row) * DD + dchunk * 8, KshP + R * 128);
  }
  // V tile: 128 d-rows x 64B, chunk m of row d stored at pos m^(d&3)
#pragma unroll
  for (int i = 0; i < 2; ++i) {
    const int D = wave * 32 + i * 16;         // 16 rows per instr
    const int dr = D + (lane >> 2);
    const int vchunk = (lane & 3) ^ ((lane >> 2) & 3);   // dr&3 == (lane>>2)&3
    dma16(Vtb + (size_t)dr * VTS + j0 + vchunk * 8, VshP + D * 32);
  }
}

// ---------- attention: DMA double-buffered, splitK=4, partials to ws -------
__global__ __launch_bounds__(256, 4) void attn_kernel(
    const float* __restrict__ Q, const short* __restrict__ Kb,
    const short* __restrict__ Vtb, const int* __restrict__ seg,
    const int* __restrict__ starts,
    float* __restrict__ Op, float* __restrict__ lp) {
  __shared__ __align__(16) short Ksh[2][32 * 128];   // 16 KB (swizzled)
  __shared__ __align__(16) short Vsh[2][128 * 32];   // 16 KB (swizzled)
  __shared__ __align__(16) short Ps[4][16 * PS_LD];  // 5 KB per-wave P

  const int tid = threadIdx.x;
  const int wave = tid >> 6;
  const int lane = tid & 63;
  const int c = lane & 15;
  const int quad = lane >> 4;

  // bid = xcd + 8*y; XCD x gets 24 contiguous row-groups (L2 segment reuse)
  const int bid = blockIdx.x;
  const int y = bid >> 3;
  const int rg = (bid & 7) * 24 + (y >> 2);
  const int sk = y & 3;                       // split-K index
  const int i0 = rg * 64;
  const int i0w = i0 + wave * 16;

  // key range of this WG's 64 rows, then this split's 32-chunk slice
  const int L = starts[seg[i0]];
  const int H = starts[seg[i0 + 63] + 1];
  const int Lm = L & ~31;
  const int nck = (H - Lm + 31) >> 5;
  const int ck0 = (nck * sk) >> 2;
  const int ck1 = (nck * (sk + 1)) >> 2;
  const int nt = ck1 - ck0;                   // tiles for this split (uniform)

  // per-row key ranges for masking
  int st_r[4], en_r[4];
#pragma unroll
  for (int r = 0; r < 4; ++r) {
    int s = seg[i0w + quad * 4 + r];
    st_r[r] = starts[s];
    en_r[r] = starts[s + 1];
  }

  // resident Q A-frags for this wave's 16 rows
  short8 qf[4];
  {
    const float* qrow = Q + (size_t)(i0w + c) * DD + quad * 8;
#pragma unroll
    for (int kc = 0; kc < 4; ++kc) qf[kc] = ld8_bf16(qrow + kc * 32);
  }

  float4v acc[8];
#pragma unroll
  for (int n = 0; n < 8; ++n) acc[n] = (float4v){0.f, 0.f, 0.f, 0.f};
  float l_part[4] = {0.f, 0.f, 0.f, 0.f};

  const float scale = 0.08838834764831845f;   // 1/sqrt(128)

  if (nt > 0)
    issue_tile(Kb, Vtb, &Ksh[0][0], &Vsh[0][0], Lm + ck0 * 32, wave, lane);
  __syncthreads();   // drains tile-0 DMA (vmcnt(0) before s_barrier)

  for (int t = 0; t < nt; ++t) {
    const int j0 = Lm + (ck0 + t) * 32;
    const int p = t & 1;
    if (t + 1 < nt)
      issue_tile(Kb, Vtb, &Ksh[p ^ 1][0], &Vsh[p ^ 1][0], j0 + 32, wave, lane);

    // --- S = Q K^T (16 rows x 32 keys), K from swizzled LDS ---
    float4v s0 = (float4v){0.f, 0.f, 0.f, 0.f};
    float4v s1 = (float4v){0.f, 0.f, 0.f, 0.f};
    const short* Kp = &Ksh[p][0];
#pragma unroll
    for (int kc = 0; kc < 4; ++kc) {
      const int pos = ((kc * 4 + quad) ^ c) * 8;
      short8 b0 = *(const short8*)(Kp + c * 128 + pos);          // keys j0+c
      short8 b1 = *(const short8*)(Kp + (16 + c) * 128 + pos);   // keys j0+16+c
      s0 = __builtin_amdgcn_mfma_f32_16x16x32_bf16(qf[kc], b0, s0, 0, 0, 0);
      s1 = __builtin_amdgcn_mfma_f32_16x16x32_bf16(qf[kc], b1, s1, 0, 0, 0);
    }

    // --- mask (range compare), exp, l partials, P -> LDS (C->A layout) ---
    const int ja = j0 + c, jb = ja + 16;
    short* prow = &Ps[wave][0];
#pragma unroll
    for (int r = 0; r < 4; ++r) {
      float pa = (ja >= st_r[r] && ja < en_r[r]) ? __expf(s0[r] * scale) : 0.f;
      float pb = (jb >= st_r[r] && jb < en_r[r]) ? __expf(s1[r] * scale) : 0.f;
      l_part[r] += pa + pb;
      int row = quad * 4 + r;
      prow[row * PS_LD + c]      = f2bf(pa);
      prow[row * PS_LD + 16 + c] = f2bf(pb);
    }
    short8 pf = *(const short8*)&Ps[wave][c * PS_LD + quad * 8];

    // --- O += P V, V^T from swizzled LDS ---
    const short* Vp = &Vsh[p][0];
    const int vpos = (quad ^ (c & 3)) * 8;
#pragma unroll
    for (int n = 0; n < 8; ++n) {
      short8 vf = *(const short8*)(Vp + (n * 16 + c) * 32 + vpos);
      acc[n] = __builtin_amdgcn_mfma_f32_16x16x32_bf16(pf, vf, acc[n], 0, 0, 0);
    }

    __syncthreads();  // drains next-tile DMA + all LDS reads before overwrite
  }

  // in-wave l reduction over the 16 key-columns
  float lrow[4];
#pragma unroll
  for (int r = 0; r < 4; ++r) {
    float l = l_part[r];
    l += __shfl_xor(l, 1, 64);
    l += __shfl_xor(l, 2, 64);
    l += __shfl_xor(l, 4, 64);
    l += __shfl_xor(l, 8, 64);
    lrow[r] = l;
  }

  // write fp32 partials (always, even nt==0: clears ws poison)
  float* OpW = Op + ((size_t)sk * NN + i0w) * DD;
#pragma unroll
  for (int n = 0; n < 8; ++n)
#pragma unroll
    for (int r = 0; r < 4; ++r)
      OpW[(quad * 4 + r) * DD + n * 16 + c] = acc[n][r];
  if (c == 0) {
#pragma unroll
    for (int r = 0; r < 4; ++r) lp[sk * NN + i0w + quad * 4 + r] = lrow[r];
  }
}

// ---------- combine: out = (sum_s Op[s]) / (sum_s lp[s] + eps) ----------
__global__ __launch_bounds__(256) void combine_kernel(
    const float* __restrict__ Op, const float* __restrict__ lp,
    float* __restrict__ out) {
  const int idx = blockIdx.x * 256 + threadIdx.x;
#pragma unroll
  for (int rep = 0; rep < 2; ++rep) {
    int u = idx + rep * 196608;              // [12288 rows][32 f4-cols]
    int row = u >> 5, c4 = (u & 31) * 4;
    float l = lp[row] + lp[NN + row] + lp[2 * NN + row] + lp[3 * NN + row];
    float4v o = (float4v){0.f, 0.f, 0.f, 0.f};
#pragma unroll
    for (int s = 0; s < 4; ++s) {
      float4v t = *(const float4v*)(Op + ((size_t)s * NN + row) * DD + c4);
      o[0] += t[0]; o[1] += t[1]; o[2] += t[2]; o[3] += t[3];
    }
    float inv = 1.f / (l + 1e-8f);
    o[0] *= inv; o[1] *= inv; o[2] *= inv; o[3] *= inv;
    *(float4v*)(out + (size_t)row * DD + c4) = o;
  }
}

// ---------- fallback (verified R1 kernel) if ws_size is too small ----------
#define KT_LD 136
#define VT_LD 40
typedef __attribute__((ext_vector_type(4))) short short4v;

__global__ __launch_bounds__(256) void attn_fallback(
    const float* __restrict__ Q, const float* __restrict__ K,
    const float* __restrict__ V, const int* __restrict__ seg,
    float* __restrict__ out) {
  __shared__ __align__(16) short Kt[32 * KT_LD];
  __shared__ __align__(16) short Vt[DD * VT_LD];
  __shared__ __align__(16) short Ps[4][16 * PS_LD];
  const int tid = threadIdx.x, wave = tid >> 6, lane = tid & 63;
  const int c = lane & 15, quad = lane >> 4;
  const int m0 = blockIdx.x * 64, i0 = m0 + wave * 16;
  const int segFirst = seg[m0], segLast = seg[m0 + 63];
  int lo = 0, hb = NN;
  while (lo < hb) { int mid = (lo + hb) >> 1; if (seg[mid] < segFirst) lo = mid + 1; else hb = mid; }
  int hi = lo, hb2 = NN;
  while (hi < hb2) { int mid = (hi + hb2) >> 1; if (seg[mid] <= segLast) hi = mid + 1; else hb2 = mid; }
  short8 qf[4];
  const float* qrow = Q + (size_t)(i0 + c) * DD + quad * 8;
#pragma unroll
  for (int kc = 0; kc < 4; ++kc) qf[kc] = ld8_bf16(qrow + kc * 32);
  int seg_r[4];
#pragma unroll
  for (int r = 0; r < 4; ++r) seg_r[r] = seg[i0 + quad * 4 + r];
  float4v acc[8];
#pragma unroll
  for (int n = 0; n < 8; ++n) acc[n] = (float4v){0.f, 0.f, 0.f, 0.f};
  float l_part[4] = {0.f, 0.f, 0.f, 0.f};
  const float scale = 0.08838834764831845f;
  for (int j0 = lo; j0 < hi; j0 += 32) {
    __syncthreads();
    {
      int row = tid >> 3, ch = tid & 7;
      int jj = j0 + row; if (jj > NN - 1) jj = NN - 1;
      const float* kp = K + (size_t)jj * DD + ch * 16;
      short* dst = &Kt[row * KT_LD + ch * 16];
#pragma unroll
      for (int q4 = 0; q4 < 4; ++q4) {
        float4v f = *(const float4v*)(kp + q4 * 4);
        short4v s;
        s[0] = f2bf(f[0]); s[1] = f2bf(f[1]); s[2] = f2bf(f[2]); s[3] = f2bf(f[3]);
        *(short4v*)(dst + q4 * 4) = s;
      }
    }
    {
      int d = tid & 127, jh = tid >> 7;
      float vv[16];
#pragma unroll
      for (int j = 0; j < 16; ++j) {
        int jj = j0 + jh * 16 + j; if (jj > NN - 1) jj = NN - 1;
        vv[j] = V[(size_t)jj * DD + d];
      }
      short8 a, b2;
#pragma unroll
      for (int j = 0; j < 8; ++j) { a[j] = f2bf(vv[j]); b2[j] = f2bf(vv[8 + j]); }
      *(short8*)&Vt[d * VT_LD + jh * 16] = a;
      *(short8*)&Vt[d * VT_LD + jh * 16 + 8] = b2;
    }
    __syncthreads();
    float4v s0 = (float4v){0.f, 0.f, 0.f, 0.f};
    float4v s1 = (float4v){0.f, 0.f, 0.f, 0.f};
    const short* krow0 = &Kt[c * KT_LD + quad * 8];
    const short* krow1 = &Kt[(16 + c) * KT_LD + quad * 8];
#pragma unroll
    for (int kc = 0; kc < 4; ++kc) {
      short8 b0 = *(const short8*)(krow0 + kc * 32);
      short8 b1 = *(const short8*)(krow1 + kc * 32);
      s0 = __builtin_amdgcn_mfma_f32_16x16x32_bf16(qf[kc], b0, s0, 0, 0, 0);
      s1 = __builtin_amdgcn_mfma_f32_16x16x32_bf16(qf[kc], b1, s1, 0, 0, 0);
    }
    int ja = j0 + c, jb = ja + 16;
    int sa = seg[ja < NN ? ja : NN - 1];
    int sb = seg[jb < NN ? jb : NN - 1];
    bool va = ja < hi, vb = jb < hi;
    short* prow = &Ps[wave][0];
#pragma unroll
    for (int r = 0; r < 4; ++r) {
      float pa = (va && sa == seg_r[r]) ? __expf(s0[r] * scale) : 0.f;
      float pb = (vb && sb == seg_r[r]) ? __expf(s1[r] * scale) : 0.f;
      l_part[r] += pa + pb;
      int row = quad * 4 + r;
      prow[row * PS_LD + c] = f2bf(pa);
      prow[row * PS_LD + 16 + c] = f2bf(pb);
    }
    short8 pf = *(const short8*)&Ps[wave][c * PS_LD + quad * 8];
#pragma unroll
    for (int n = 0; n < 8; ++n) {
      short8 vfr = *(const short8*)&Vt[(n * 16 + c) * VT_LD + quad * 8];
      acc[n] = __builtin_amdgcn_mfma_f32_16x16x32_bf16(pf, vfr, acc[n], 0, 0, 0);
    }
  }
  float linv[4];
#pragma unroll
  for (int r = 0; r < 4; ++r) {
    float l = l_part[r];
    l += __shfl_xor(l, 1, 64);
    l += __shfl_xor(l, 2, 64);
    l += __shfl_xor(l, 4, 64);
    l += __shfl_xor(l, 8, 64);
    linv[r] = 1.f / (l + 1e-8f);
  }
#pragma unroll
  for (int n = 0; n < 8; ++n)
#pragma unroll
    for (int r = 0; r < 4; ++r)
      out[(size_t)(i0 + quad * 4 + r) * DD + n * 16 + c] = acc[n][r] * linv[r];
}

extern "C" void kernel_launch(void* const* d_in, const int* in_sizes, int n_in,
                              void* d_out, int out_size, void* d_ws, size_t ws_size,
                              hipStream_t stream) {
  const float* Q = (const float*)d_in[0];
  const float* K = (const float*)d_in[1];
  const float* V = (const float*)d_in[2];
  const int* seg = (const int*)d_in[4];
  float* out = (float*)d_out;

  const size_t kb_bytes = (size_t)NN * DD * sizeof(short);    // 3,145,728
  const size_t vt_bytes = (size_t)DD * VTS * sizeof(short);   // 3,180,544
  const size_t st_bytes = 64 * sizeof(int);                   // 256
  const size_t op_bytes = (size_t)4 * NN * DD * sizeof(float);  // 25,165,824
  const size_t lp_bytes = (size_t)4 * NN * sizeof(float);       // 196,608
  const size_t need = kb_bytes + vt_bytes + st_bytes + op_bytes + lp_bytes;

  if (ws_size >= need) {
    char* w = (char*)d_ws;
    short* Kb  = (short*)w;                     w += kb_bytes;
    short* Vtb = (short*)w;                     w += vt_bytes;
    int* starts = (int*)w;                      w += st_bytes;
    float* Op = (float*)w;                      w += op_bytes;
    float* lp = (float*)w;
    prep_kernel<<<864 + NN / 256, 256, 0, stream>>>(K, V, seg, Kb, Vtb, starts);
    attn_kernel<<<768, 256, 0, stream>>>(Q, Kb, Vtb, seg, starts, Op, lp);
    combine_kernel<<<768, 256, 0, stream>>>(Op, lp, out);
  } else {
    attn_fallback<<<NN / 64, 256, 0, stream>>>(Q, K, V, seg, out);
  }
}

// Round 10
// 95.157 us; speedup vs baseline: 2.3294x; 1.0038x over previous
//
#include <hip/hip_runtime.h>

// ExactAttention: block-diagonal masked softmax(Q K^T / sqrt(d)) @ V
// N=12288, D=128, 32 sorted batch segments, fp32 in/out.
// Global-max/EPS deviation ~1e-8 relative -> plain masked softmax.
//
// R10 = R9 (prep -> DMA-pipelined attn (splitK=4, 4 WG/CU) -> combine) with
// split-K O-partials stored as bf16 instead of fp32: halves Op traffic
// (25.2 -> 12.6 MB round-trip). Partials are ~400-term positive sums, bf16
// adds ~0.2% rel error (~5e-4 on output; threshold 1.5e-2). lp stays fp32.
// NO device-scope fences anywhere (R8: +125us from cross-XCD L2 writeback).

#define NN 12288
#define DD 128
#define NB 32
#define PS_LD 40
#define VTS 12424   // Vtb row stride (shorts): spreads L2 channels c -> c%16

typedef __attribute__((ext_vector_type(8))) short short8;
typedef __attribute__((ext_vector_type(4))) float float4v;

__device__ __forceinline__ short f2bf(float f) {
  unsigned u = __builtin_bit_cast(unsigned, f);
  return (short)((u + 0x7FFFu + ((u >> 16) & 1u)) >> 16);
}

__device__ __forceinline__ float bf2f(short s) {
  return __builtin_bit_cast(float, ((unsigned)(unsigned short)s) << 16);
}

__device__ __forceinline__ short8 ld8_bf16(const float* p) {
  float4v f0 = *(const float4v*)p;
  float4v f1 = *(const float4v*)(p + 4);
  short8 s;
  s[0] = f2bf(f0[0]); s[1] = f2bf(f0[1]); s[2] = f2bf(f0[2]); s[3] = f2bf(f0[3]);
  s[4] = f2bf(f1[0]); s[5] = f2bf(f1[1]); s[6] = f2bf(f1[2]); s[7] = f2bf(f1[3]);
  return s;
}

// async global->LDS DMA, 16B/lane: lds dest = uniform base + lane*16.
__device__ __forceinline__ void dma16(const short* gsrc, short* ldst) {
  auto g = (const __attribute__((address_space(1))) void*)(unsigned long long)gsrc;
  auto l = (__attribute__((address_space(3))) void*)(unsigned)(unsigned long long)ldst;
  __builtin_amdgcn_global_load_lds(g, l, 16, 0, 0);
}

// ---------- prep: Kb = bf16(K); Vtb = bf16(V)^T (stride VTS); starts[] -----
__global__ __launch_bounds__(256) void prep_kernel(
    const float* __restrict__ K, const float* __restrict__ V,
    const int* __restrict__ seg,
    short* __restrict__ Kb, short* __restrict__ Vtb, int* __restrict__ starts) {
  const int tid = threadIdx.x;
  const int b = blockIdx.x;
  if (b < 768) {
    const size_t base = (size_t)b * 2048 + (size_t)tid * 8;
    *(short8*)(Kb + base) = ld8_bf16(K + base);
  } else if (b < 864) {
    __shared__ __align__(16) short Ts[DD * 136];
    const int kt = (b - 768) * 128;
#pragma unroll
    for (int rep = 0; rep < 16; ++rep) {
      int v = rep * 256 + tid;            // [128 keys][32 float4-cols]
      int key = v >> 5, c4 = (v & 31) * 4;
      float4v f = *(const float4v*)(V + (size_t)(kt + key) * DD + c4);
      Ts[(c4 + 0) * 136 + key] = f2bf(f[0]);
      Ts[(c4 + 1) * 136 + key] = f2bf(f[1]);
      Ts[(c4 + 2) * 136 + key] = f2bf(f[2]);
      Ts[(c4 + 3) * 136 + key] = f2bf(f[3]);
    }
    __syncthreads();
    const int c16 = (tid & 15) * 8;
#pragma unroll
    for (int rep = 0; rep < 8; ++rep) {
      int d = rep * 16 + (tid >> 4);
      short8 s = *(const short8*)&Ts[d * 136 + c16];
      *(short8*)(Vtb + (size_t)d * VTS + kt + c16) = s;
    }
  } else {
    int i = (b - 864) * 256 + tid;
    int s = seg[i];
    int sp = (i == 0) ? -1 : seg[i - 1];
    for (int bb = sp + 1; bb <= s; ++bb) starts[bb] = i;
    if (i == NN - 1)
      for (int bb = s + 1; bb <= NB; ++bb) starts[bb] = NN;
  }
}

// issue one 32-key tile's DMAs (this wave's quarter: 2 K-instr + 2 V-instr)
__device__ __forceinline__ void issue_tile(
    const short* __restrict__ Kb, const short* __restrict__ Vtb,
    short* KshP, short* VshP, int j0, int wave, int lane) {
  // K tile: 32 rows x 256B, chunk m of row r stored at pos m^(r&15)
#pragma unroll
  for (int i = 0; i < 2; ++i) {
    const int R = wave * 8 + i * 4;           // 4 rows per instr
    const int row = R + (lane >> 4);
    const int dchunk = (lane & 15) ^ (row & 15);
    dma16(Kb + (size_t)(j0 + row) * DD + dchunk * 8, KshP + R * 128);
  }
  // V tile: 128 d-rows x 64B, chunk m of row d stored at pos m^(d&3)
#pragma unroll
  for (int i = 0; i < 2; ++i) {
    const int D = wave * 32 + i * 16;         // 16 rows per instr
    const int dr = D + (lane >> 2);
    const int vchunk = (lane & 3) ^ ((lane >> 2) & 3);   // dr&3 == (lane>>2)&3
    dma16(Vtb + (size_t)dr * VTS + j0 + vchunk * 8, VshP + D * 32);
  }
}

// ---------- attention: DMA double-buffered, splitK=4, bf16 partials -------
__global__ __launch_bounds__(256, 4) void attn_kernel(
    const float* __restrict__ Q, const short* __restrict__ Kb,
    const short* __restrict__ Vtb, const int* __restrict__ seg,
    const int* __restrict__ starts,
    short* __restrict__ Op, float* __restrict__ lp) {
  __shared__ __align__(16) short Ksh[2][32 * 128];   // 16 KB (swizzled)
  __shared__ __align__(16) short Vsh[2][128 * 32];   // 16 KB (swizzled)
  __shared__ __align__(16) short Ps[4][16 * PS_LD];  // 5 KB per-wave P

  const int tid = threadIdx.x;
  const int wave = tid >> 6;
  const int lane = tid & 63;
  const int c = lane & 15;
  const int quad = lane >> 4;

  // bid = xcd + 8*y; XCD x gets 24 contiguous row-groups (L2 segment reuse)
  const int bid = blockIdx.x;
  const int y = bid >> 3;
  const int rg = (bid & 7) * 24 + (y >> 2);
  const int sk = y & 3;                       // split-K index
  const int i0 = rg * 64;
  const int i0w = i0 + wave * 16;

  // key range of this WG's 64 rows, then this split's 32-chunk slice
  const int L = starts[seg[i0]];
  const int H = starts[seg[i0 + 63] + 1];
  const int Lm = L & ~31;
  const int nck = (H - Lm + 31) >> 5;
  const int ck0 = (nck * sk) >> 2;
  const int ck1 = (nck * (sk + 1)) >> 2;
  const int nt = ck1 - ck0;                   // tiles for this split (uniform)

  // per-row key ranges for masking
  int st_r[4], en_r[4];
#pragma unroll
  for (int r = 0; r < 4; ++r) {
    int s = seg[i0w + quad * 4 + r];
    st_r[r] = starts[s];
    en_r[r] = starts[s + 1];
  }

  // resident Q A-frags for this wave's 16 rows
  short8 qf[4];
  {
    const float* qrow = Q + (size_t)(i0w + c) * DD + quad * 8;
#pragma unroll
    for (int kc = 0; kc < 4; ++kc) qf[kc] = ld8_bf16(qrow + kc * 32);
  }

  float4v acc[8];
#pragma unroll
  for (int n = 0; n < 8; ++n) acc[n] = (float4v){0.f, 0.f, 0.f, 0.f};
  float l_part[4] = {0.f, 0.f, 0.f, 0.f};

  const float scale = 0.08838834764831845f;   // 1/sqrt(128)

  if (nt > 0)
    issue_tile(Kb, Vtb, &Ksh[0][0], &Vsh[0][0], Lm + ck0 * 32, wave, lane);
  __syncthreads();   // drains tile-0 DMA (vmcnt(0) before s_barrier)

  for (int t = 0; t < nt; ++t) {
    const int j0 = Lm + (ck0 + t) * 32;
    const int p = t & 1;
    if (t + 1 < nt)
      issue_tile(Kb, Vtb, &Ksh[p ^ 1][0], &Vsh[p ^ 1][0], j0 + 32, wave, lane);

    // --- S = Q K^T (16 rows x 32 keys), K from swizzled LDS ---
    float4v s0 = (float4v){0.f, 0.f, 0.f, 0.f};
    float4v s1 = (float4v){0.f, 0.f, 0.f, 0.f};
    const short* Kp = &Ksh[p][0];
#pragma unroll
    for (int kc = 0; kc < 4; ++kc) {
      const int pos = ((kc * 4 + quad) ^ c) * 8;
      short8 b0 = *(const short8*)(Kp + c * 128 + pos);          // keys j0+c
      short8 b1 = *(const short8*)(Kp + (16 + c) * 128 + pos);   // keys j0+16+c
      s0 = __builtin_amdgcn_mfma_f32_16x16x32_bf16(qf[kc], b0, s0, 0, 0, 0);
      s1 = __builtin_amdgcn_mfma_f32_16x16x32_bf16(qf[kc], b1, s1, 0, 0, 0);
    }

    // --- mask (range compare), exp, l partials, P -> LDS (C->A layout) ---
    const int ja = j0 + c, jb = ja + 16;
    short* prow = &Ps[wave][0];
#pragma unroll
    for (int r = 0; r < 4; ++r) {
      float pa = (ja >= st_r[r] && ja < en_r[r]) ? __expf(s0[r] * scale) : 0.f;
      float pb = (jb >= st_r[r] && jb < en_r[r]) ? __expf(s1[r] * scale) : 0.f;
      l_part[r] += pa + pb;
      int row = quad * 4 + r;
      prow[row * PS_LD + c]      = f2bf(pa);
      prow[row * PS_LD + 16 + c] = f2bf(pb);
    }
    short8 pf = *(const short8*)&Ps[wave][c * PS_LD + quad * 8];

    // --- O += P V, V^T from swizzled LDS ---
    const short* Vp = &Vsh[p][0];
    const int vpos = (quad ^ (c & 3)) * 8;
#pragma unroll
    for (int n = 0; n < 8; ++n) {
      short8 vf = *(const short8*)(Vp + (n * 16 + c) * 32 + vpos);
      acc[n] = __builtin_amdgcn_mfma_f32_16x16x32_bf16(pf, vf, acc[n], 0, 0, 0);
    }

    __syncthreads();  // drains next-tile DMA + all LDS reads before overwrite
  }

  // in-wave l reduction over the 16 key-columns
  float lrow[4];
#pragma unroll
  for (int r = 0; r < 4; ++r) {
    float l = l_part[r];
    l += __shfl_xor(l, 1, 64);
    l += __shfl_xor(l, 2, 64);
    l += __shfl_xor(l, 4, 64);
    l += __shfl_xor(l, 8, 64);
    lrow[r] = l;
  }

  // write bf16 partials (always, even nt==0: clears ws poison)
  short* OpW = Op + ((size_t)sk * NN + i0w) * DD;
#pragma unroll
  for (int n = 0; n < 8; ++n)
#pragma unroll
    for (int r = 0; r < 4; ++r)
      OpW[(quad * 4 + r) * DD + n * 16 + c] = f2bf(acc[n][r]);
  if (c == 0) {
#pragma unroll
    for (int r = 0; r < 4; ++r) lp[sk * NN + i0w + quad * 4 + r] = lrow[r];
  }
}

// ---------- combine: out = (sum_s bf2f(Op[s])) / (sum_s lp[s] + eps) -------
__global__ __launch_bounds__(256) void combine_kernel(
    const short* __restrict__ Op, const float* __restrict__ lp,
    float* __restrict__ out) {
  const int u = blockIdx.x * 256 + threadIdx.x;   // [12288 rows][16 chunk8]
  const int row = u >> 4, c8 = (u & 15) * 8;
  float l = lp[row] + lp[NN + row] + lp[2 * NN + row] + lp[3 * NN + row];
  float o[8] = {0.f, 0.f, 0.f, 0.f, 0.f, 0.f, 0.f, 0.f};
#pragma unroll
  for (int s = 0; s < 4; ++s) {
    short8 t = *(const short8*)(Op + ((size_t)s * NN + row) * DD + c8);
#pragma unroll
    for (int j = 0; j < 8; ++j) o[j] += bf2f(t[j]);
  }
  const float inv = 1.f / (l + 1e-8f);
  float4v o0 = (float4v){o[0] * inv, o[1] * inv, o[2] * inv, o[3] * inv};
  float4v o1 = (float4v){o[4] * inv, o[5] * inv, o[6] * inv, o[7] * inv};
  *(float4v*)(out + (size_t)row * DD + c8)     = o0;
  *(float4v*)(out + (size_t)row * DD + c8 + 4) = o1;
}

// ---------- fallback (verified R1 kernel) if ws_size is too small ----------
#define KT_LD 136
#define VT_LD 40
typedef __attribute__((ext_vector_type(4))) short short4v;

__global__ __launch_bounds__(256) void attn_fallback(
    const float* __restrict__ Q, const float* __restrict__ K,
    const float* __restrict__ V, const int* __restrict__ seg,
    float* __restrict__ out) {
  __shared__ __align__(16) short Kt[32 * KT_LD];
  __shared__ __align__(16) short Vt[DD * VT_LD];
  __shared__ __align__(16) short Ps[4][16 * PS_LD];
  const int tid = threadIdx.x, wave = tid >> 6, lane = tid & 63;
  const int c = lane & 15, quad = lane >> 4;
  const int m0 = blockIdx.x * 64, i0 = m0 + wave * 16;
  const int segFirst = seg[m0], segLast = seg[m0 + 63];
  int lo = 0, hb = NN;
  while (lo < hb) { int mid = (lo + hb) >> 1; if (seg[mid] < segFirst) lo = mid + 1; else hb = mid; }
  int hi = lo, hb2 = NN;
  while (hi < hb2) { int mid = (hi + hb2) >> 1; if (seg[mid] <= segLast) hi = mid + 1; else hb2 = mid; }
  short8 qf[4];
  const float* qrow = Q + (size_t)(i0 + c) * DD + quad * 8;
#pragma unroll
  for (int kc = 0; kc < 4; ++kc) qf[kc] = ld8_bf16(qrow + kc * 32);
  int seg_r[4];
#pragma unroll
  for (int r = 0; r < 4; ++r) seg_r[r] = seg[i0 + quad * 4 + r];
  float4v acc[8];
#pragma unroll
  for (int n = 0; n < 8; ++n) acc[n] = (float4v){0.f, 0.f, 0.f, 0.f};
  float l_part[4] = {0.f, 0.f, 0.f, 0.f};
  const float scale = 0.08838834764831845f;
  for (int j0 = lo; j0 < hi; j0 += 32) {
    __syncthreads();
    {
      int row = tid >> 3, ch = tid & 7;
      int jj = j0 + row; if (jj > NN - 1) jj = NN - 1;
      const float* kp = K + (size_t)jj * DD + ch * 16;
      short* dst = &Kt[row * KT_LD + ch * 16];
#pragma unroll
      for (int q4 = 0; q4 < 4; ++q4) {
        float4v f = *(const float4v*)(kp + q4 * 4);
        short4v s;
        s[0] = f2bf(f[0]); s[1] = f2bf(f[1]); s[2] = f2bf(f[2]); s[3] = f2bf(f[3]);
        *(short4v*)(dst + q4 * 4) = s;
      }
    }
    {
      int d = tid & 127, jh = tid >> 7;
      float vv[16];
#pragma unroll
      for (int j = 0; j < 16; ++j) {
        int jj = j0 + jh * 16 + j; if (jj > NN - 1) jj = NN - 1;
        vv[j] = V[(size_t)jj * DD + d];
      }
      short8 a, b2;
#pragma unroll
      for (int j = 0; j < 8; ++j) { a[j] = f2bf(vv[j]); b2[j] = f2bf(vv[8 + j]); }
      *(short8*)&Vt[d * VT_LD + jh * 16] = a;
      *(short8*)&Vt[d * VT_LD + jh * 16 + 8] = b2;
    }
    __syncthreads();
    float4v s0 = (float4v){0.f, 0.f, 0.f, 0.f};
    float4v s1 = (float4v){0.f, 0.f, 0.f, 0.f};
    const short* krow0 = &Kt[c * KT_LD + quad * 8];
    const short* krow1 = &Kt[(16 + c) * KT_LD + quad * 8];
#pragma unroll
    for (int kc = 0; kc < 4; ++kc) {
      short8 b0 = *(const short8*)(krow0 + kc * 32);
      short8 b1 = *(const short8*)(krow1 + kc * 32);
      s0 = __builtin_amdgcn_mfma_f32_16x16x32_bf16(qf[kc], b0, s0, 0, 0, 0);
      s1 = __builtin_amdgcn_mfma_f32_16x16x32_bf16(qf[kc], b1, s1, 0, 0, 0);
    }
    int ja = j0 + c, jb = ja + 16;
    int sa = seg[ja < NN ? ja : NN - 1];
    int sb = seg[jb < NN ? jb : NN - 1];
    bool va = ja < hi, vb = jb < hi;
    short* prow = &Ps[wave][0];
#pragma unroll
    for (int r = 0; r < 4; ++r) {
      float pa = (va && sa == seg_r[r]) ? __expf(s0[r] * scale) : 0.f;
      float pb = (vb && sb == seg_r[r]) ? __expf(s1[r] * scale) : 0.f;
      l_part[r] += pa + pb;
      int row = quad * 4 + r;
      prow[row * PS_LD + c] = f2bf(pa);
      prow[row * PS_LD + 16 + c] = f2bf(pb);
    }
    short8 pf = *(const short8*)&Ps[wave][c * PS_LD + quad * 8];
#pragma unroll
    for (int n = 0; n < 8; ++n) {
      short8 vfr = *(const short8*)&Vt[(n * 16 + c) * VT_LD + quad * 8];
      acc[n] = __builtin_amdgcn_mfma_f32_16x16x32_bf16(pf, vfr, acc[n], 0, 0, 0);
    }
  }
  float linv[4];
#pragma unroll
  for (int r = 0; r < 4; ++r) {
    float l = l_part[r];
    l += __shfl_xor(l, 1, 64);
    l += __shfl_xor(l, 2, 64);
    l += __shfl_xor(l, 4, 64);
    l += __shfl_xor(l, 8, 64);
    linv[r] = 1.f / (l + 1e-8f);
  }
#pragma unroll
  for (int n = 0; n < 8; ++n)
#pragma unroll
    for (int r = 0; r < 4; ++r)
      out[(size_t)(i0 + quad * 4 + r) * DD + n * 16 + c] = acc[n][r] * linv[r];
}

extern "C" void kernel_launch(void* const* d_in, const int* in_sizes, int n_in,
                              void* d_out, int out_size, void* d_ws, size_t ws_size,
                              hipStream_t stream) {
  const float* Q = (const float*)d_in[0];
  const float* K = (const float*)d_in[1];
  const float* V = (const float*)d_in[2];
  const int* seg = (const int*)d_in[4];
  float* out = (float*)d_out;

  const size_t kb_bytes = (size_t)NN * DD * sizeof(short);      // 3,145,728
  const size_t vt_bytes = (size_t)DD * VTS * sizeof(short);     // 3,180,544
  const size_t st_bytes = 64 * sizeof(int);                     // 256
  const size_t op_bytes = (size_t)4 * NN * DD * sizeof(short);  // 12,582,912
  const size_t lp_bytes = (size_t)4 * NN * sizeof(float);       // 196,608
  const size_t need = kb_bytes + vt_bytes + st_bytes + op_bytes + lp_bytes;

  if (ws_size >= need) {
    char* w = (char*)d_ws;
    short* Kb  = (short*)w;                     w += kb_bytes;
    short* Vtb = (short*)w;                     w += vt_bytes;
    int* starts = (int*)w;                      w += st_bytes;
    short* Op = (short*)w;                      w += op_bytes;
    float* lp = (float*)w;
    prep_kernel<<<864 + NN / 256, 256, 0, stream>>>(K, V, seg, Kb, Vtb, starts);
    attn_kernel<<<768, 256, 0, stream>>>(Q, Kb, Vtb, seg, starts, Op, lp);
    combine_kernel<<<768, 256, 0, stream>>>(Op, lp, out);
  } else {
    attn_fallback<<<NN / 64, 256, 0, stream>>>(Q, K, V, seg, out);
  }
}